// Round 5
// baseline (29.600 us; speedup 1.0000x reference)
//
#include <hip/hip_runtime.h>

// SoftTimeAttention: out[b,q,:] = sum_j softmax_j(-(T*(t_q-t_j))^2) * h[b,j,:]
// B=4, T=4096, H=256, f32. w = exp(-x^2), x = 4096*(t_q-t_j); x > 12 => w == 0
// exactly in f32. Single-kernel design: each block owns 4 t-buckets (1/1024
// wide); it scans the batch t-array, stages all keys within +-3 buckets into
// LDS (exact f32 window), then each wave processes one bucket's queries with
// a ballot-compacted weighted-row accumulation.

constexpr int Bb  = 4;
constexpr int Tt  = 4096;
constexpr int Hh  = 256;
constexpr int NBK = 1024;     // buckets per batch, width = 4 in scaled units
constexpr int BPB = 4;        // buckets per block
constexpr int MCAND = 512;    // LDS candidate cap  (expected ~40)
constexpr int MQ    = 256;    // LDS query cap      (expected ~16)

__device__ __forceinline__ int bucket_of(float ts) {
    int kk = (int)(ts * 0.25f);
    return kk < 0 ? 0 : (kk > NBK - 1 ? NBK - 1 : kk);
}

// Accumulation for one pass of <=NQ queries against the staged candidates.
template<int NQ>
__device__ __forceinline__ void process_pass(
    const uint2* __restrict__ candL, int nc,
    const float* __restrict__ hb,
    const float* tq, const int* qi, int got, int lane,
    float* __restrict__ outb)
{
    float4 acc[NQ];
    float  den[NQ];
    #pragma unroll
    for (int g = 0; g < NQ; ++g) { acc[g] = make_float4(0.f,0.f,0.f,0.f); den[g] = 0.f; }

    for (int base = 0; base < nc; base += 64) {
        const int p = base + lane;
        const bool v = p < nc;
        uint2 ce;
        ce.x = __float_as_uint(3.0e18f); ce.y = 0u;   // dummy -> w == 0 exactly
        if (v) ce = candL[p];
        const float tj = __uint_as_float(ce.x);
        const int   jj = (int)ce.y;

        float w[NQ]; float wmax = 0.f;
        #pragma unroll
        for (int g = 0; g < NQ; ++g) {
            const float x = tq[g] - tj;
            w[g] = __expf(-x * x);
            den[g] += w[g];
            wmax = fmaxf(wmax, w[g]);
        }

        unsigned long long mask = __ballot(wmax > 1e-30f);
        while (mask) {
            const int s0 = __builtin_ctzll(mask); mask &= mask - 1;
            const bool h1 = mask != 0;
            const int s1 = h1 ? __builtin_ctzll(mask) : s0; if (h1) mask &= mask - 1;
            const bool h2 = mask != 0;
            const int s2 = h2 ? __builtin_ctzll(mask) : s0; if (h2) mask &= mask - 1;
            const bool h3 = mask != 0;
            const int s3 = h3 ? __builtin_ctzll(mask) : s0; if (h3) mask &= mask - 1;

            const int j0 = __shfl(jj, s0);
            const int j1 = __shfl(jj, s1);
            const int j2 = __shfl(jj, s2);
            const int j3 = __shfl(jj, s3);
            float4 h0  = *(const float4*)&hb[(size_t)j0 * Hh + lane * 4];
            float4 h1v = *(const float4*)&hb[(size_t)j1 * Hh + lane * 4];
            float4 h2v = *(const float4*)&hb[(size_t)j2 * Hh + lane * 4];
            float4 h3v = *(const float4*)&hb[(size_t)j3 * Hh + lane * 4];
            if (!h1) h1v = make_float4(0.f,0.f,0.f,0.f);
            if (!h2) h2v = make_float4(0.f,0.f,0.f,0.f);
            if (!h3) h3v = make_float4(0.f,0.f,0.f,0.f);

            #pragma unroll
            for (int g = 0; g < NQ; ++g) {
                const float a0 = __shfl(w[g], s0);
                const float a1 = __shfl(w[g], s1);
                const float a2 = __shfl(w[g], s2);
                const float a3 = __shfl(w[g], s3);
                acc[g].x += a0 * h0.x + a1 * h1v.x + a2 * h2v.x + a3 * h3v.x;
                acc[g].y += a0 * h0.y + a1 * h1v.y + a2 * h2v.y + a3 * h3v.y;
                acc[g].z += a0 * h0.z + a1 * h1v.z + a2 * h2v.z + a3 * h3v.z;
                acc[g].w += a0 * h0.w + a1 * h1v.w + a2 * h2v.w + a3 * h3v.w;
            }
        }
    }

    #pragma unroll
    for (int g = 0; g < NQ; ++g) {
        float d = den[g];
        #pragma unroll
        for (int s = 1; s < 64; s <<= 1) d += __shfl_xor(d, s);
        den[g] = d;
    }

    #pragma unroll
    for (int g = 0; g < NQ; ++g) {      // constant-index unroll (rule #20)
        if (g < got) {
            const float inv = 1.0f / den[g];
            float* orow = outb + (size_t)qi[g] * Hh + lane * 4;
            float4 o;
            o.x = acc[g].x * inv; o.y = acc[g].y * inv;
            o.z = acc[g].z * inv; o.w = acc[g].w * inv;
            *(float4*)orow = o;
        }
    }
}

__global__ __launch_bounds__(256) void stattn_onepass(
    const float* __restrict__ h_seq,
    const float* __restrict__ tvals,
    float* __restrict__ out)
{
    __shared__ uint2 candL[MCAND];
    __shared__ unsigned short qloc[MQ];
    __shared__ int nc_s, nq_s, ovf_s;

    const int tid  = threadIdx.x;
    const int lane = tid & 63;
    const int wv   = tid >> 6;

    // XCD-contiguous swizzle: 1024 blocks -> 128 contiguous per XCD,
    // 2 XCDs per batch so the 4 MB h panel is L2-resident.
    const int phys = blockIdx.x;
    const int lb   = (phys & 7) * 128 + (phys >> 3);
    const int b    = lb >> 8;
    const int m    = lb & 255;
    const int k0   = m * BPB;

    const float* tb   = tvals + (size_t)b * Tt;
    const float* hb   = h_seq + (size_t)b * Tt * Hh;
    float*       outb = out   + (size_t)b * Tt * Hh;

    if (tid == 0) { nc_s = 0; nq_s = 0; ovf_s = 0; }
    __syncthreads();

    // ---- scan batch t, stage window candidates + queries into LDS
    for (int c = 0; c < 4; ++c) {
        const int j4 = c * 1024 + tid * 4;
        const float4 tv = *(const float4*)&tb[j4];
        #pragma unroll
        for (int u = 0; u < 4; ++u) {
            const float t  = (&tv.x)[u];
            const float ts = t * 4096.0f;
            const int   kk = bucket_of(ts);
            if (kk >= k0 - 3 && kk <= k0 + 6) {
                const int r = atomicAdd(&nc_s, 1);
                if (r < MCAND) {
                    uint2 pr; pr.x = __float_as_uint(ts); pr.y = (unsigned)(j4 + u);
                    candL[r] = pr;
                    if (kk >= k0 && kk < k0 + BPB) {
                        const int rq = atomicAdd(&nq_s, 1);
                        if (rq < MQ) qloc[rq] = (unsigned short)r;
                        else ovf_s = 1;
                    }
                } else ovf_s = 1;
            }
        }
    }
    __syncthreads();

    const int nc = nc_s < MCAND ? nc_s : MCAND;
    const int nq = nq_s < MQ ? nq_s : MQ;

    if (ovf_s) {
        // ---- exact dense fallback (never triggers for this input; keeps the
        // kernel correct for any input). Wave wv handles queries j % 4 == wv.
        for (int j = wv; j < Tt; j += 4) {
            const float tsq = tb[j] * 4096.0f;
            const int   kk  = bucket_of(tsq);
            if (kk < k0 || kk >= k0 + BPB) continue;
            float4 acc = make_float4(0.f,0.f,0.f,0.f);
            float  den = 0.f;
            for (int key = 0; key < Tt; ++key) {
                const float x = tsq - tb[key] * 4096.0f;
                const float w = __expf(-x * x);
                den += w;
                if (w > 0.f) {
                    const float4 hv = *(const float4*)&hb[(size_t)key * Hh + lane * 4];
                    acc.x += w * hv.x; acc.y += w * hv.y;
                    acc.z += w * hv.z; acc.w += w * hv.w;
                }
            }
            const float inv = 1.0f / den;
            float4 o;
            o.x = acc.x * inv; o.y = acc.y * inv;
            o.z = acc.z * inv; o.w = acc.w * inv;
            *(float4*)&outb[(size_t)j * Hh + lane * 4] = o;
        }
        return;
    }

    // ---- fast path: wave wv owns bucket k0+wv
    const int k = k0 + wv;
    int e = 0;                       // wave-uniform cursor into qloc
    while (true) {
        float tq[8]; int qi[8];
        int got = 0;
        #pragma unroll
        for (int g = 0; g < 8; ++g) {    // constant-index gather (rule #20)
            float ts_f = -3.0e18f;       // sentinel -> w == 0 exactly
            int   id   = 0;
            bool  found = false;
            while (e < nq) {
                const int cl = qloc[e]; ++e;
                const uint2 ce = candL[cl];
                const float t2 = __uint_as_float(ce.x);
                if (bucket_of(t2) == k) { ts_f = t2; id = (int)ce.y; found = true; break; }
            }
            tq[g] = ts_f; qi[g] = id;
            if (found) got = g + 1;
        }
        if (got == 0) break;

        if (got <= 4) process_pass<4>(candL, nc, hb, tq, qi, got, lane, outb);
        else          process_pass<8>(candL, nc, hb, tq, qi, got, lane, outb);

        if (e >= nq) break;
    }
}

extern "C" void kernel_launch(void* const* d_in, const int* in_sizes, int n_in,
                              void* d_out, int out_size, void* d_ws, size_t ws_size,
                              hipStream_t stream) {
    const float* h_seq = (const float*)d_in[0];
    const float* tvals = (const float*)d_in[1];
    float* out = (float*)d_out;
    // grid = B * (NBK / BPB) = 4 * 256 = 1024 blocks, 256 threads (4 waves)
    stattn_onepass<<<dim3(Bb * (NBK / BPB)), dim3(256), 0, stream>>>(h_seq, tvals, out);
    (void)d_ws; (void)ws_size; (void)in_sizes; (void)n_in; (void)out_size;
}